// Round 8
// baseline (162.034 us; speedup 1.0000x reference)
//
#include <hip/hip_runtime.h>

typedef unsigned short u16;
typedef unsigned int   u32;
typedef __attribute__((ext_vector_type(8))) short short8;   // 8 bf16 = 4 VGPRs
typedef __attribute__((ext_vector_type(4))) float f32x4;

#define NB    4      // batch
#define NCH   256    // channels
#define NHD   8      // heads
#define HD    32     // head dim
#define NSP   2304   // H*W
#define NBH   32     // NB*NHD
#define NKT   36     // total 64-wide K tiles
#define KPW   9      // K tiles per wave (4-wave in-block k-split)

// round-to-nearest-even fp32 -> bf16 bits
__device__ __forceinline__ u16 f2bf(float f) {
    u32 u = __float_as_uint(f);
    u += 0x7FFFu + ((u >> 16) & 1u);
    return (u16)(u >> 16);
}
__device__ __forceinline__ u32 pack2(float a, float b) {
    return (u32)f2bf(a) | ((u32)f2bf(b) << 16);
}
// fast pack two fp32 -> bf16x2: hw cvt (RNE) if present, else 1-instr v_perm truncate.
// e in [1, 2.7]; rowsum (MFMA over the SAME packed values) stays consistent with P.
__device__ __forceinline__ u32 pkfast(float a, float b) {
#if __has_builtin(__builtin_amdgcn_cvt_pk_bf16_f32)
    typedef __attribute__((ext_vector_type(2))) __bf16 bf2;
    union { bf2 v; u32 u; } cv;
    cv.v = __builtin_amdgcn_cvt_pk_bf16_f32(a, b);
    return cv.u;
#else
    return __builtin_amdgcn_perm(__float_as_uint(b), __float_as_uint(a), 0x07060302u);
#endif
}
__device__ __forceinline__ float fexp2(float x) {
#if __has_builtin(__builtin_amdgcn_exp2f)
    return __builtin_amdgcn_exp2f(x);
#else
    return exp2f(x);
#endif
}

// ---------------- prep: normalize q,k (temp*log2e folded into q); v -> sigma-permuted
// tiles (coalesced via LDS transpose); p==3 slice casts proj_w -> bf16.
// grid (NSP/256, 4, NBH), block 256.
__global__ __launch_bounds__(256) void prep_kernel(
    const float* __restrict__ qkv, const float* __restrict__ temp,
    const float* __restrict__ projw,
    u16* __restrict__ Qn, u16* __restrict__ Kn, u16* __restrict__ Vp,
    u16* __restrict__ Wb)
{
    const int p  = blockIdx.y;
    const int bh = blockIdx.z, b = bh >> 3, head = bh & 7;

    if (p == 3) {   // proj_w cast: 16384 float4 chunks spread over 9*32 blocks
        const int idx = (bh * (NSP / 256) + blockIdx.x) * 256 + threadIdx.x;
        if (idx < NCH * NCH / 4) {
            float4 v = ((const float4*)projw)[idx];
            ((uint2*)Wb)[idx] = make_uint2(pack2(v.x, v.y), pack2(v.z, v.w));
        }
        return;
    }

    const int n = blockIdx.x * 256 + threadIdx.x;
    const float* src = qkv + ((size_t)(b * 3 * NCH + p * NCH + head * HD)) * NSP + n;

    float v[HD];
#pragma unroll
    for (int d = 0; d < HD; ++d) v[d] = src[(size_t)d * NSP];

    if (p == 2) {
        // sigma-permuted V tile: word = d*64 + pos(kr); pos = c*32+qd*8+jj encodes
        // column kr = c*32 + (jj<4 ? qd*4+jj : 16+qd*4+(jj-4)). Build in LDS (2B
        // scatter, cheap), then write 64B/lane fully-coalesced global stores.
        __shared__ u16 Lt[4][32][72];   // 4 tiles x (32 d x 64 cols, row-padded to 72)
        const int tile = threadIdx.x >> 6;     // one tile per wave
        const int r6 = threadIdx.x & 63;       // column within tile
        const int c = r6 >> 5, r5 = r6 & 31;
        const int qd = (r5 < 16) ? (r5 >> 2) : ((r5 - 16) >> 2);
        const int jj = (r5 < 16) ? (r5 & 3) : (4 + (r5 & 3));
        const int pos = c * 32 + qd * 8 + jj;
#pragma unroll
        for (int d = 0; d < HD; ++d) Lt[tile][d][pos] = f2bf(v[d]);
        __syncthreads();
        const int dd = r6 >> 1, half = r6 & 1;
        const uint4* lsrc = (const uint4*)&Lt[tile][dd][half * 32];
        const int gt = blockIdx.x * 4 + tile;
        uint4* dst = (uint4*)(Vp + (size_t)bh * NSP * HD + (size_t)gt * 2048 + dd * 64 + half * 32);
#pragma unroll
        for (int i = 0; i < 4; ++i) dst[i] = lsrc[i];
    } else {
        float s = 0.f;
#pragma unroll
        for (int d = 0; d < HD; ++d) s += v[d] * v[d];
        float sc = 1.f / fmaxf(sqrtf(s), 1e-12f);
        if (p == 0) sc *= temp[head] * 1.44269504088896f;   // fold temp*log2e into q
        u32 pk[HD / 2];
#pragma unroll
        for (int i = 0; i < HD / 2; ++i) pk[i] = pack2(v[2 * i] * sc, v[2 * i + 1] * sc);
        u16* dst = (p == 0 ? Qn : Kn) + ((size_t)bh * NSP + n) * HD;
#pragma unroll
        for (int i = 0; i < 4; ++i) ((uint4*)dst)[i] = ((const uint4*)pk)[i];
    }
}

// ---------------- flash attention: 32 q-rows/block, 4-way k-split ----------------
// block = 256 thr (4 waves), grid (NBH, NSP/32). blockIdx.x = bh (linear%8 == bh%8,
// gridDim.x=32) -> all blocks of a bh on one XCD; 4 bh/XCD -> K/V L2-resident (1.2 MB).
// All 4 waves own the SAME 32 q-rows (2 q-tiles); wave w covers k-tiles [w*9,w*9+9).
// Partials combine linearly (exp(relu)/sum: no running max) -> one epilogue barrier;
// waves 0,1 reduce + write q-tile t2==w.
// Small wave state (~100 regs: 24 acc + ka 16 + vb 16 + qf 8) -> ~5 waves/SIMD
// WITHOUT launch_bounds caps (r7 lesson: forcing 128 regs spilled, WRITE 114 MB) and
// WITHOUT prefetch regs (r6 lesson). Occupancy, not pipelining, hides L2 latency.
// S^T = K.Q; C/D (col=q=l15, row=kr=quad*4+r) feeds PV directly as A-frag under
// k-permutation sigma; V B-frags come sigma-permuted from prep. Rowsum via MFMA
// against all-ones B.
__global__ __launch_bounds__(256) void attn_kernel(
    const u16* __restrict__ Qn, const u16* __restrict__ Kn,
    const u16* __restrict__ Vp, u16* __restrict__ X)
{
    __shared__ float cmb[4][64][25];   // [wave][lane][t2*12 + {4 O0,4 O1,4 rs}] pad 25
    const int bh = blockIdx.x, b = bh >> 3, head = bh & 7;
    const int w = threadIdx.x >> 6, lane = threadIdx.x & 63;
    const int l15 = lane & 15, quad = lane >> 4;
    const int qbase = blockIdx.y * 32;

    const u16* Kg = Kn + (size_t)bh * NSP * HD + (size_t)w * KPW * 2048 + l15 * HD + quad * 8;
    const u16* Vg = Vp + (size_t)bh * NSP * HD + (size_t)w * KPW * 2048 + l15 * 64 + quad * 8;

    short8 qf[2];
#pragma unroll
    for (int t2 = 0; t2 < 2; ++t2)
        qf[t2] = *(const short8*)(Qn + ((size_t)bh * NSP + qbase + t2 * 16 + l15) * HD + quad * 8);

    const short one = (short)0x3F80;   // bf16 1.0
    const short8 vones = {one, one, one, one, one, one, one, one};
    const f32x4 zf = {0.f, 0.f, 0.f, 0.f};

    f32x4 oacc[2][2] = {{{0,0,0,0},{0,0,0,0}},{{0,0,0,0},{0,0,0,0}}};
    f32x4 rsac[2]    = {{0,0,0,0},{0,0,0,0}};

    for (int kt = 0; kt < KPW; ++kt) {
        // K first (consumed first), V second (consumed after S+exp chain)
        short8 ka[4];
#pragma unroll
        for (int i = 0; i < 4; ++i)
            ka[i] = *(const short8*)(Kg + (size_t)kt * 2048 + i * 512);
        short8 vb[2][2];
#pragma unroll
        for (int c = 0; c < 2; ++c)
#pragma unroll
            for (int h = 0; h < 2; ++h)
                vb[c][h] = *(const short8*)(Vg + (size_t)kt * 2048 + h * 1024 + c * 32);

#pragma unroll
        for (int t2 = 0; t2 < 2; ++t2) {
            f32x4 sf[4];
#pragma unroll
            for (int i = 0; i < 4; ++i)
                sf[i] = __builtin_amdgcn_mfma_f32_16x16x32_bf16(ka[i], qf[t2], zf, 0, 0, 0);
            u32 pk[4][2];
#pragma unroll
            for (int i = 0; i < 4; ++i) {
                pk[i][0] = pkfast(fexp2(fmaxf(sf[i][0], 0.f)), fexp2(fmaxf(sf[i][1], 0.f)));
                pk[i][1] = pkfast(fexp2(fmaxf(sf[i][2], 0.f)), fexp2(fmaxf(sf[i][3], 0.f)));
            }
#pragma unroll
            for (int c = 0; c < 2; ++c) {
                union { short8 s; u32 u[4]; } pa;
                pa.u[0] = pk[2 * c][0];     pa.u[1] = pk[2 * c][1];
                pa.u[2] = pk[2 * c + 1][0]; pa.u[3] = pk[2 * c + 1][1];
                oacc[t2][0] = __builtin_amdgcn_mfma_f32_16x16x32_bf16(pa.s, vb[c][0], oacc[t2][0], 0, 0, 0);
                oacc[t2][1] = __builtin_amdgcn_mfma_f32_16x16x32_bf16(pa.s, vb[c][1], oacc[t2][1], 0, 0, 0);
                rsac[t2]    = __builtin_amdgcn_mfma_f32_16x16x32_bf16(pa.s, vones,    rsac[t2],    0, 0, 0);
            }
        }
    }

    // publish both q-tile partials; waves 0,1 reduce + write q-tile t2 == w
    {
        float* my = &cmb[w][lane][0];
#pragma unroll
        for (int t2 = 0; t2 < 2; ++t2) {
#pragma unroll
            for (int h = 0; h < 2; ++h)
#pragma unroll
                for (int r = 0; r < 4; ++r) my[t2 * 12 + h * 4 + r] = oacc[t2][h][r];
#pragma unroll
            for (int r = 0; r < 4; ++r) my[t2 * 12 + 8 + r] = rsac[t2][r];
        }
    }
    __syncthreads();
    if (w < 2) {
        const int t2 = w;
        float o0[4] = {0,0,0,0}, o1[4] = {0,0,0,0}, rsum[4] = {0,0,0,0};
#pragma unroll
        for (int j = 0; j < 4; ++j) {
            const float* srcp = &cmb[j][lane][t2 * 12];
#pragma unroll
            for (int r = 0; r < 4; ++r) {
                o0[r]   += srcp[r];
                o1[r]   += srcp[4 + r];
                rsum[r] += srcp[8 + r];
            }
        }
        u16* Xb = X + (size_t)b * NSP * NCH + head * HD;
#pragma unroll
        for (int r = 0; r < 4; ++r) {
            const float inv = 1.f / rsum[r];
            u16* row = Xb + (size_t)(qbase + t2 * 16 + quad * 4 + r) * NCH;
            row[l15]      = f2bf(o0[r] * inv);
            row[16 + l15] = f2bf(o1[r] * inv);
        }
    }
}

// ---------------- 1x1 conv: out[b,o,n] = sum_c W[o,c] X[b,n,c] + bias[o] ----------------
// grid (NSP/64, NCH/64, NB), block 256 (4 waves): wave w does 16 o x 64 n.
__global__ __launch_bounds__(256) void proj_kernel(
    const u16* __restrict__ Wb, const u16* __restrict__ X,
    const float* __restrict__ bias, float* __restrict__ out)
{
    const int b = blockIdx.z;
    const int w = threadIdx.x >> 6, lane = threadIdx.x & 63;
    const int l15 = lane & 15, quad = lane >> 4;
    const int obase = blockIdx.y * 64 + w * 16;
    const int nbase = blockIdx.x * 64;

    const u16* wrow = Wb + (size_t)(obase + l15) * NCH + quad * 8;
    const u16* xrow = X + ((size_t)b * NSP + nbase + l15) * NCH + quad * 8;

    f32x4 acc[4] = {{0,0,0,0},{0,0,0,0},{0,0,0,0},{0,0,0,0}};
#pragma unroll
    for (int ks = 0; ks < 8; ++ks) {
        const short8 af = *(const short8*)(wrow + ks * 32);
#pragma unroll
        for (int jn = 0; jn < 4; ++jn) {
            const short8 bf = *(const short8*)(xrow + (size_t)jn * 16 * NCH + ks * 32);
            acc[jn] = __builtin_amdgcn_mfma_f32_16x16x32_bf16(af, bf, acc[jn], 0, 0, 0);
        }
    }
#pragma unroll
    for (int r = 0; r < 4; ++r) {
        const int o = obase + quad * 4 + r;
        const float bo = bias[o];
        float* orow = out + ((size_t)b * NCH + o) * NSP + nbase;
#pragma unroll
        for (int jn = 0; jn < 4; ++jn)
            orow[jn * 16 + l15] = acc[jn][r] + bo;
    }
}

extern "C" void kernel_launch(void* const* d_in, const int* in_sizes, int n_in,
                              void* d_out, int out_size, void* d_ws, size_t ws_size,
                              hipStream_t stream) {
    const float* qkv   = (const float*)d_in[0];
    const float* temp  = (const float*)d_in[1];
    const float* projw = (const float*)d_in[2];
    const float* projb = (const float*)d_in[3];
    float* out = (float*)d_out;

    // workspace: Qn | Kn | Vp | X (each 2,359,296 bf16) | Wb (65,536 bf16)  ~19 MB
    u16* Qn = (u16*)d_ws;
    u16* Kn = Qn + (size_t)NBH * NSP * HD;
    u16* Vp = Kn + (size_t)NBH * NSP * HD;
    u16* X  = Vp + (size_t)NBH * NSP * HD;
    u16* Wb = X + (size_t)NB * NSP * NCH;

    prep_kernel<<<dim3(NSP / 256, 4, NBH), dim3(256), 0, stream>>>(qkv, temp, projw, Qn, Kn, Vp, Wb);
    attn_kernel<<<dim3(NBH, NSP / 32), dim3(256), 0, stream>>>(Qn, Kn, Vp, X);
    proj_kernel<<<dim3(NSP / 64, NCH / 64, NB), dim3(256), 0, stream>>>(Wb, X, projb, out);
}

// Round 9
// 161.221 us; speedup vs baseline: 1.0050x; 1.0050x over previous
//
#include <hip/hip_runtime.h>

typedef unsigned short u16;
typedef unsigned int   u32;
typedef __attribute__((ext_vector_type(8))) short short8;   // 8 bf16 = 4 VGPRs
typedef __attribute__((ext_vector_type(4))) float f32x4;

#define NB    4      // batch
#define NCH   256    // channels
#define NHD   8      // heads
#define HD    32     // head dim
#define NSP   2304   // H*W
#define NBH   32     // NB*NHD
#define NKT   36     // total 64-wide K tiles
#define KPW   9      // K tiles per wave (4-wave in-block k-split)

// round-to-nearest-even fp32 -> bf16 bits
__device__ __forceinline__ u16 f2bf(float f) {
    u32 u = __float_as_uint(f);
    u += 0x7FFFu + ((u >> 16) & 1u);
    return (u16)(u >> 16);
}
__device__ __forceinline__ u32 pack2(float a, float b) {
    return (u32)f2bf(a) | ((u32)f2bf(b) << 16);
}
// exp2(relu(x)) packed to bf16x2 in minimal instrs: v_max, v_exp, v_cvt_pk_bf16_f32.
__device__ __forceinline__ float fexp2(float x) {
#if __has_builtin(__builtin_amdgcn_exp2f)
    return __builtin_amdgcn_exp2f(x);
#else
    return exp2f(x);
#endif
}
__device__ __forceinline__ u32 pexp2(float a, float b) {
    float ea = fexp2(fmaxf(a, 0.f));
    float eb = fexp2(fmaxf(b, 0.f));
#if __has_builtin(__builtin_amdgcn_cvt_pk_bf16_f32)
    typedef __attribute__((ext_vector_type(2))) __bf16 bf2;
    union { bf2 v; u32 u; } cv;
    cv.v = __builtin_amdgcn_cvt_pk_bf16_f32(ea, eb);
    return cv.u;
#else
    return __builtin_amdgcn_perm(__float_as_uint(eb), __float_as_uint(ea), 0x07060302u);
#endif
}

// ---------------- prep: normalize q,k (temp*log2e folded into q); v -> sigma-permuted
// tiles (coalesced via LDS transpose); p==3 slice casts proj_w -> bf16.
// grid (NSP/256, 4, NBH), block 256.
__global__ __launch_bounds__(256) void prep_kernel(
    const float* __restrict__ qkv, const float* __restrict__ temp,
    const float* __restrict__ projw,
    u16* __restrict__ Qn, u16* __restrict__ Kn, u16* __restrict__ Vp,
    u16* __restrict__ Wb)
{
    const int p  = blockIdx.y;
    const int bh = blockIdx.z, b = bh >> 3, head = bh & 7;

    if (p == 3) {   // proj_w cast: 16384 float4 chunks spread over 9*32 blocks
        const int idx = (bh * (NSP / 256) + blockIdx.x) * 256 + threadIdx.x;
        if (idx < NCH * NCH / 4) {
            float4 v = ((const float4*)projw)[idx];
            ((uint2*)Wb)[idx] = make_uint2(pack2(v.x, v.y), pack2(v.z, v.w));
        }
        return;
    }

    const int n = blockIdx.x * 256 + threadIdx.x;
    const float* src = qkv + ((size_t)(b * 3 * NCH + p * NCH + head * HD)) * NSP + n;

    float v[HD];
#pragma unroll
    for (int d = 0; d < HD; ++d) v[d] = src[(size_t)d * NSP];

    if (p == 2) {
        // sigma-permuted V tile: word = d*64 + pos(kr); pos = c*32+qd*8+jj encodes
        // column kr = c*32 + (jj<4 ? qd*4+jj : 16+qd*4+(jj-4)). Build in LDS (2B
        // scatter, cheap), then write 64B/lane fully-coalesced global stores.
        __shared__ u16 Lt[4][32][72];   // 4 tiles x (32 d x 64 cols, row-padded to 72)
        const int tile = threadIdx.x >> 6;     // one tile per wave
        const int r6 = threadIdx.x & 63;       // column within tile
        const int c = r6 >> 5, r5 = r6 & 31;
        const int qd = (r5 < 16) ? (r5 >> 2) : ((r5 - 16) >> 2);
        const int jj = (r5 < 16) ? (r5 & 3) : (4 + (r5 & 3));
        const int pos = c * 32 + qd * 8 + jj;
#pragma unroll
        for (int d = 0; d < HD; ++d) Lt[tile][d][pos] = f2bf(v[d]);
        __syncthreads();
        const int dd = r6 >> 1, half = r6 & 1;
        const uint4* lsrc = (const uint4*)&Lt[tile][dd][half * 32];
        const int gt = blockIdx.x * 4 + tile;
        uint4* dst = (uint4*)(Vp + (size_t)bh * NSP * HD + (size_t)gt * 2048 + dd * 64 + half * 32);
#pragma unroll
        for (int i = 0; i < 4; ++i) dst[i] = lsrc[i];
    } else {
        float s = 0.f;
#pragma unroll
        for (int d = 0; d < HD; ++d) s += v[d] * v[d];
        float sc = 1.f / fmaxf(sqrtf(s), 1e-12f);
        if (p == 0) sc *= temp[head] * 1.44269504088896f;   // fold temp*log2e into q
        u32 pk[HD / 2];
#pragma unroll
        for (int i = 0; i < HD / 2; ++i) pk[i] = pack2(v[2 * i] * sc, v[2 * i + 1] * sc);
        u16* dst = (p == 0 ? Qn : Kn) + ((size_t)bh * NSP + n) * HD;
#pragma unroll
        for (int i = 0; i < 4; ++i) ((uint4*)dst)[i] = ((const uint4*)pk)[i];
    }
}

// ---------------- flash attention: 64 q-rows/wave, 4-way k-split (r5 shape) ----------
// block = 256 thr (4 waves), grid (NBH, NSP/64). blockIdx.x = bh (linear%8 == bh%8) so
// all q-blocks of a bh share one XCD -> K/V L2-resident (1.2 MB/XCD).
// All 4 waves own the SAME 64 q-rows (4 q-tiles); wave w covers k-tiles [w*9,w*9+9).
// Partials combine linearly (exp(relu)/sum: no running max) -> one epilogue barrier;
// wave w reduces + writes q-tile t2==w; publish only 3 non-own tiles (38 KB LDS).
// S^T = K.Q; C/D (col=q=l15, row=kr=quad*4+r) feeds PV directly as A-frag under
// k-permutation sigma; V B-frags come sigma-permuted from prep. Rowsum via MFMA
// against all-ones B. K prefetched 1 tile ahead (r5-proven); NO launch_bounds cap,
// NO unroll pragma (r6/r7: both force spills, WRITE_SIZE 72-114 MB).
// Inner loop trimmed: fused max->exp->cvt_pk into pa construction (no pk[][] array),
// pointer-bump addressing (no per-iter kt* folds).
__global__ __launch_bounds__(256) void attn_kernel(
    const u16* __restrict__ Qn, const u16* __restrict__ Kn,
    const u16* __restrict__ Vp, u16* __restrict__ X)
{
    __shared__ float cmb[4][64][37];   // [wave][lane][slot*12 + {4 O0,4 O1,4 rs}] pad 37
    const int bh = blockIdx.x, b = bh >> 3, head = bh & 7;
    const int w = threadIdx.x >> 6, lane = threadIdx.x & 63;
    const int l15 = lane & 15, quad = lane >> 4;
    const int qbase = blockIdx.y * 64;

    const u16* Kg = Kn + (size_t)bh * NSP * HD + (size_t)w * KPW * 2048 + l15 * HD + quad * 8;
    const u16* Vg = Vp + (size_t)bh * NSP * HD + (size_t)w * KPW * 2048 + l15 * 64 + quad * 8;

    short8 qf[4];
#pragma unroll
    for (int t2 = 0; t2 < 4; ++t2)
        qf[t2] = *(const short8*)(Qn + ((size_t)bh * NSP + qbase + t2 * 16 + l15) * HD + quad * 8);

    const short one = (short)0x3F80;   // bf16 1.0
    const short8 vones = {one, one, one, one, one, one, one, one};
    const f32x4 zf = {0.f, 0.f, 0.f, 0.f};

    f32x4 oacc[4][2] = {{{0,0,0,0},{0,0,0,0}},{{0,0,0,0},{0,0,0,0}},
                        {{0,0,0,0},{0,0,0,0}},{{0,0,0,0},{0,0,0,0}}};
    f32x4 rsac[4]    = {{0,0,0,0},{0,0,0,0},{0,0,0,0},{0,0,0,0}};

    // preload K tile 0
    short8 ka[4];
#pragma unroll
    for (int i = 0; i < 4; ++i) ka[i] = *(const short8*)(Kg + i * 512);

    for (int kt = 0; kt < KPW; ++kt) {
        // V for THIS tile (consumed after the S+exp chain: latency self-hiding)
        short8 vb[2][2];
#pragma unroll
        for (int c = 0; c < 2; ++c)
#pragma unroll
            for (int h = 0; h < 2; ++h)
                vb[c][h] = *(const short8*)(Vg + h * 1024 + c * 32);
        Vg += 2048;
        // K for NEXT tile
        short8 kan[4];
        if (kt + 1 < KPW) {
            Kg += 2048;
#pragma unroll
            for (int i = 0; i < 4; ++i) kan[i] = *(const short8*)(Kg + i * 512);
        }

#pragma unroll
        for (int t2 = 0; t2 < 4; ++t2) {
            f32x4 sf[4];
#pragma unroll
            for (int i = 0; i < 4; ++i)
                sf[i] = __builtin_amdgcn_mfma_f32_16x16x32_bf16(ka[i], qf[t2], zf, 0, 0, 0);
#pragma unroll
            for (int c = 0; c < 2; ++c) {
                union { short8 s; u32 u[4]; } pa;
                pa.u[0] = pexp2(sf[2 * c][0],     sf[2 * c][1]);
                pa.u[1] = pexp2(sf[2 * c][2],     sf[2 * c][3]);
                pa.u[2] = pexp2(sf[2 * c + 1][0], sf[2 * c + 1][1]);
                pa.u[3] = pexp2(sf[2 * c + 1][2], sf[2 * c + 1][3]);
                oacc[t2][0] = __builtin_amdgcn_mfma_f32_16x16x32_bf16(pa.s, vb[c][0], oacc[t2][0], 0, 0, 0);
                oacc[t2][1] = __builtin_amdgcn_mfma_f32_16x16x32_bf16(pa.s, vb[c][1], oacc[t2][1], 0, 0, 0);
                rsac[t2]    = __builtin_amdgcn_mfma_f32_16x16x32_bf16(pa.s, vones,    rsac[t2],    0, 0, 0);
            }
        }

        if (kt + 1 < KPW) {
#pragma unroll
            for (int i = 0; i < 4; ++i) ka[i] = kan[i];
        }
    }

    // publish the 3 non-own q-tiles; wave w reduces + writes q-tile t2 == w
    {
        float* my = &cmb[w][lane][0];
#pragma unroll
        for (int s = 0; s < 3; ++s) {
            const int t2 = s + (s >= w ? 1 : 0);
#pragma unroll
            for (int h = 0; h < 2; ++h)
#pragma unroll
                for (int r = 0; r < 4; ++r) my[s * 12 + h * 4 + r] = oacc[t2][h][r];
#pragma unroll
            for (int r = 0; r < 4; ++r) my[s * 12 + 8 + r] = rsac[t2][r];
        }
    }
    __syncthreads();
    {
        const int t2 = w;
        float o0[4], o1[4], rsum[4];
#pragma unroll
        for (int r = 0; r < 4; ++r) {
            o0[r] = oacc[t2][0][r]; o1[r] = oacc[t2][1][r]; rsum[r] = rsac[t2][r];
        }
#pragma unroll
        for (int j = 0; j < 4; ++j) {
            if (j == w) continue;
            const int slot = w - (w > j ? 1 : 0);
            const float* srcp = &cmb[j][lane][slot * 12];
#pragma unroll
            for (int r = 0; r < 4; ++r) {
                o0[r]   += srcp[r];
                o1[r]   += srcp[4 + r];
                rsum[r] += srcp[8 + r];
            }
        }
        u16* Xb = X + (size_t)b * NSP * NCH + head * HD;
#pragma unroll
        for (int r = 0; r < 4; ++r) {
            const float inv = 1.f / rsum[r];
            u16* row = Xb + (size_t)(qbase + t2 * 16 + quad * 4 + r) * NCH;
            row[l15]      = f2bf(o0[r] * inv);
            row[16 + l15] = f2bf(o1[r] * inv);
        }
    }
}

// ---------------- 1x1 conv: out[b,o,n] = sum_c W[o,c] X[b,n,c] + bias[o] ----------------
// grid (NSP/64, NCH/64, NB), block 256 (4 waves): wave w does 16 o x 64 n.
__global__ __launch_bounds__(256) void proj_kernel(
    const u16* __restrict__ Wb, const u16* __restrict__ X,
    const float* __restrict__ bias, float* __restrict__ out)
{
    const int b = blockIdx.z;
    const int w = threadIdx.x >> 6, lane = threadIdx.x & 63;
    const int l15 = lane & 15, quad = lane >> 4;
    const int obase = blockIdx.y * 64 + w * 16;
    const int nbase = blockIdx.x * 64;

    const u16* wrow = Wb + (size_t)(obase + l15) * NCH + quad * 8;
    const u16* xrow = X + ((size_t)b * NSP + nbase + l15) * NCH + quad * 8;

    f32x4 acc[4] = {{0,0,0,0},{0,0,0,0},{0,0,0,0},{0,0,0,0}};
#pragma unroll
    for (int ks = 0; ks < 8; ++ks) {
        const short8 af = *(const short8*)(wrow + ks * 32);
#pragma unroll
        for (int jn = 0; jn < 4; ++jn) {
            const short8 bf = *(const short8*)(xrow + (size_t)jn * 16 * NCH + ks * 32);
            acc[jn] = __builtin_amdgcn_mfma_f32_16x16x32_bf16(af, bf, acc[jn], 0, 0, 0);
        }
    }
#pragma unroll
    for (int r = 0; r < 4; ++r) {
        const int o = obase + quad * 4 + r;
        const float bo = bias[o];
        float* orow = out + ((size_t)b * NCH + o) * NSP + nbase;
#pragma unroll
        for (int jn = 0; jn < 4; ++jn)
            orow[jn * 16 + l15] = acc[jn][r] + bo;
    }
}

extern "C" void kernel_launch(void* const* d_in, const int* in_sizes, int n_in,
                              void* d_out, int out_size, void* d_ws, size_t ws_size,
                              hipStream_t stream) {
    const float* qkv   = (const float*)d_in[0];
    const float* temp  = (const float*)d_in[1];
    const float* projw = (const float*)d_in[2];
    const float* projb = (const float*)d_in[3];
    float* out = (float*)d_out;

    // workspace: Qn | Kn | Vp | X (each 2,359,296 bf16) | Wb (65,536 bf16)  ~19 MB
    u16* Qn = (u16*)d_ws;
    u16* Kn = Qn + (size_t)NBH * NSP * HD;
    u16* Vp = Kn + (size_t)NBH * NSP * HD;
    u16* X  = Vp + (size_t)NBH * NSP * HD;
    u16* Wb = X + (size_t)NB * NSP * NCH;

    prep_kernel<<<dim3(NSP / 256, 4, NBH), dim3(256), 0, stream>>>(qkv, temp, projw, Qn, Kn, Vp, Wb);
    attn_kernel<<<dim3(NBH, NSP / 64), dim3(256), 0, stream>>>(Qn, Kn, Vp, X);
    proj_kernel<<<dim3(NSP / 64, NCH / 64, NB), dim3(256), 0, stream>>>(Wb, X, projb, out);
}

// Round 10
// 150.920 us; speedup vs baseline: 1.0736x; 1.0683x over previous
//
#include <hip/hip_runtime.h>

typedef unsigned short u16;
typedef unsigned int   u32;
typedef __attribute__((ext_vector_type(8))) short short8;   // 8 bf16 = 4 VGPRs
typedef __attribute__((ext_vector_type(4))) float f32x4;

#define NB    4      // batch
#define NCH   256    // channels
#define NHD   8      // heads
#define HD    32     // head dim
#define NSP   2304   // H*W
#define NBH   32     // NB*NHD
#define NKT   36     // total 64-wide K tiles
#define KPW   9      // K tiles per wave (4-wave in-block k-split)

// round-to-nearest-even fp32 -> bf16 bits
__device__ __forceinline__ u16 f2bf(float f) {
    u32 u = __float_as_uint(f);
    u += 0x7FFFu + ((u >> 16) & 1u);
    return (u16)(u >> 16);
}
__device__ __forceinline__ u32 pack2(float a, float b) {
    return (u32)f2bf(a) | ((u32)f2bf(b) << 16);
}
// exp2(relu(x)) packed to bf16x2 in minimal instrs: v_max, v_exp, v_cvt_pk_bf16_f32.
__device__ __forceinline__ float fexp2(float x) {
#if __has_builtin(__builtin_amdgcn_exp2f)
    return __builtin_amdgcn_exp2f(x);
#else
    return exp2f(x);
#endif
}
__device__ __forceinline__ u32 pexp2(float a, float b) {
    float ea = fexp2(fmaxf(a, 0.f));
    float eb = fexp2(fmaxf(b, 0.f));
#if __has_builtin(__builtin_amdgcn_cvt_pk_bf16_f32)
    typedef __attribute__((ext_vector_type(2))) __bf16 bf2;
    union { bf2 v; u32 u; } cv;
    cv.v = __builtin_amdgcn_cvt_pk_bf16_f32(ea, eb);
    return cv.u;
#else
    return __builtin_amdgcn_perm(__float_as_uint(eb), __float_as_uint(ea), 0x07060302u);
#endif
}

// ---------------- prep: normalize q,k (temp*log2e folded into q); v -> sigma-permuted
// tiles (coalesced via LDS transpose); p==3 slice casts proj_w -> bf16.
// grid (NSP/256, 4, NBH), block 256.
__global__ __launch_bounds__(256) void prep_kernel(
    const float* __restrict__ qkv, const float* __restrict__ temp,
    const float* __restrict__ projw,
    u16* __restrict__ Qn, u16* __restrict__ Kn, u16* __restrict__ Vp,
    u16* __restrict__ Wb)
{
    const int p  = blockIdx.y;
    const int bh = blockIdx.z, b = bh >> 3, head = bh & 7;

    if (p == 3) {   // proj_w cast: 16384 float4 chunks spread over 9*32 blocks
        const int idx = (bh * (NSP / 256) + blockIdx.x) * 256 + threadIdx.x;
        if (idx < NCH * NCH / 4) {
            float4 v = ((const float4*)projw)[idx];
            ((uint2*)Wb)[idx] = make_uint2(pack2(v.x, v.y), pack2(v.z, v.w));
        }
        return;
    }

    const int n = blockIdx.x * 256 + threadIdx.x;
    const float* src = qkv + ((size_t)(b * 3 * NCH + p * NCH + head * HD)) * NSP + n;

    float v[HD];
#pragma unroll
    for (int d = 0; d < HD; ++d) v[d] = src[(size_t)d * NSP];

    if (p == 2) {
        // sigma-permuted V tile: word = d*64 + pos(kr); pos = c*32+qd*8+jj encodes
        // column kr = c*32 + (jj<4 ? qd*4+jj : 16+qd*4+(jj-4)). Build in LDS (2B
        // scatter, cheap), then write 64B/lane fully-coalesced global stores.
        __shared__ u16 Lt[4][32][72];   // 4 tiles x (32 d x 64 cols, row-padded to 72)
        const int tile = threadIdx.x >> 6;     // one tile per wave
        const int r6 = threadIdx.x & 63;       // column within tile
        const int c = r6 >> 5, r5 = r6 & 31;
        const int qd = (r5 < 16) ? (r5 >> 2) : ((r5 - 16) >> 2);
        const int jj = (r5 < 16) ? (r5 & 3) : (4 + (r5 & 3));
        const int pos = c * 32 + qd * 8 + jj;
#pragma unroll
        for (int d = 0; d < HD; ++d) Lt[tile][d][pos] = f2bf(v[d]);
        __syncthreads();
        const int dd = r6 >> 1, half = r6 & 1;
        const uint4* lsrc = (const uint4*)&Lt[tile][dd][half * 32];
        const int gt = blockIdx.x * 4 + tile;
        uint4* dst = (uint4*)(Vp + (size_t)bh * NSP * HD + (size_t)gt * 2048 + dd * 64 + half * 32);
#pragma unroll
        for (int i = 0; i < 4; ++i) dst[i] = lsrc[i];
    } else {
        float s = 0.f;
#pragma unroll
        for (int d = 0; d < HD; ++d) s += v[d] * v[d];
        float sc = 1.f / fmaxf(sqrtf(s), 1e-12f);
        if (p == 0) sc *= temp[head] * 1.44269504088896f;   // fold temp*log2e into q
        u32 pk[HD / 2];
#pragma unroll
        for (int i = 0; i < HD / 2; ++i) pk[i] = pack2(v[2 * i] * sc, v[2 * i + 1] * sc);
        u16* dst = (p == 0 ? Qn : Kn) + ((size_t)bh * NSP + n) * HD;
#pragma unroll
        for (int i = 0; i < 4; ++i) ((uint4*)dst)[i] = ((const uint4*)pk)[i];
    }
}

// ---------------- flash attention: 64 q-rows/wave, 4-way k-split (r5 shape) ----------
// block = 256 thr (4 waves), grid (NBH, NSP/64). blockIdx.x = bh (linear%8 == bh%8) so
// all q-blocks of a bh share one XCD -> K/V L2-resident (1.2 MB/XCD).
// All 4 waves own the SAME 64 q-rows (4 q-tiles); wave w covers k-tiles [w*9,w*9+9).
// Partials combine linearly (exp(relu)/sum: no running max) -> one epilogue barrier;
// wave w reduces + writes q-tile t2==w; publish only 3 non-own tiles.
// CRITICAL (r6/r9 lesson): every subscript into oacc/rsac must be COMPILE-TIME —
// runtime `oacc[t2]` (t2 from wave id) forces the acc block to scratch
// (WRITE_SIZE 62-72 MB). Wave-uniform `if (t2 == w)` guards inside unrolled
// loops keep indices literal; only LDS addresses carry runtime w.
// S^T = K.Q; C/D (col=q=l15, row=kr=quad*4+r) feeds PV directly as A-frag under
// k-permutation sigma; V B-frags come sigma-permuted from prep. Rowsum via MFMA
// against all-ones B. K prefetched 1 tile ahead; NO launch_bounds cap, NO unroll
// pragma (r7: forced caps spill).
__global__ __launch_bounds__(256) void attn_kernel(
    const u16* __restrict__ Qn, const u16* __restrict__ Kn,
    const u16* __restrict__ Vp, u16* __restrict__ X)
{
    __shared__ float cmb[4][64][37];   // [wave][lane][slot*12 + {4 O0,4 O1,4 rs}] pad 37
    const int bh = blockIdx.x, b = bh >> 3, head = bh & 7;
    const int w = threadIdx.x >> 6, lane = threadIdx.x & 63;
    const int l15 = lane & 15, quad = lane >> 4;
    const int qbase = blockIdx.y * 64;

    const u16* Kg = Kn + (size_t)bh * NSP * HD + (size_t)w * KPW * 2048 + l15 * HD + quad * 8;
    const u16* Vg = Vp + (size_t)bh * NSP * HD + (size_t)w * KPW * 2048 + l15 * 64 + quad * 8;

    short8 qf[4];
#pragma unroll
    for (int t2 = 0; t2 < 4; ++t2)
        qf[t2] = *(const short8*)(Qn + ((size_t)bh * NSP + qbase + t2 * 16 + l15) * HD + quad * 8);

    const short one = (short)0x3F80;   // bf16 1.0
    const short8 vones = {one, one, one, one, one, one, one, one};
    const f32x4 zf = {0.f, 0.f, 0.f, 0.f};

    f32x4 oacc[4][2] = {{{0,0,0,0},{0,0,0,0}},{{0,0,0,0},{0,0,0,0}},
                        {{0,0,0,0},{0,0,0,0}},{{0,0,0,0},{0,0,0,0}}};
    f32x4 rsac[4]    = {{0,0,0,0},{0,0,0,0},{0,0,0,0},{0,0,0,0}};

    // preload K tile 0
    short8 ka[4];
#pragma unroll
    for (int i = 0; i < 4; ++i) ka[i] = *(const short8*)(Kg + i * 512);

    for (int kt = 0; kt < KPW; ++kt) {
        // V for THIS tile (consumed after the S+exp chain: latency self-hiding)
        short8 vb[2][2];
#pragma unroll
        for (int c = 0; c < 2; ++c)
#pragma unroll
            for (int h = 0; h < 2; ++h)
                vb[c][h] = *(const short8*)(Vg + h * 1024 + c * 32);
        Vg += 2048;
        // K for NEXT tile
        short8 kan[4];
        if (kt + 1 < KPW) {
            Kg += 2048;
#pragma unroll
            for (int i = 0; i < 4; ++i) kan[i] = *(const short8*)(Kg + i * 512);
        }

#pragma unroll
        for (int t2 = 0; t2 < 4; ++t2) {
            f32x4 sf[4];
#pragma unroll
            for (int i = 0; i < 4; ++i)
                sf[i] = __builtin_amdgcn_mfma_f32_16x16x32_bf16(ka[i], qf[t2], zf, 0, 0, 0);
#pragma unroll
            for (int c = 0; c < 2; ++c) {
                union { short8 s; u32 u[4]; } pa;
                pa.u[0] = pexp2(sf[2 * c][0],     sf[2 * c][1]);
                pa.u[1] = pexp2(sf[2 * c][2],     sf[2 * c][3]);
                pa.u[2] = pexp2(sf[2 * c + 1][0], sf[2 * c + 1][1]);
                pa.u[3] = pexp2(sf[2 * c + 1][2], sf[2 * c + 1][3]);
                oacc[t2][0] = __builtin_amdgcn_mfma_f32_16x16x32_bf16(pa.s, vb[c][0], oacc[t2][0], 0, 0, 0);
                oacc[t2][1] = __builtin_amdgcn_mfma_f32_16x16x32_bf16(pa.s, vb[c][1], oacc[t2][1], 0, 0, 0);
                rsac[t2]    = __builtin_amdgcn_mfma_f32_16x16x32_bf16(pa.s, vones,    rsac[t2],    0, 0, 0);
            }
        }

        if (kt + 1 < KPW) {
#pragma unroll
            for (int i = 0; i < 4; ++i) ka[i] = kan[i];
        }
    }

    // publish the 3 non-own q-tiles (compile-time t2, wave-uniform guard)
    {
        float* my = &cmb[w][lane][0];
#pragma unroll
        for (int t2 = 0; t2 < 4; ++t2) {
            if (t2 == w) continue;                     // wave-uniform branch
            const int slot = t2 - (t2 > w ? 1 : 0);    // runtime LDS offset: OK
            float* dst = my + slot * 12;
#pragma unroll
            for (int h = 0; h < 2; ++h)
#pragma unroll
                for (int r = 0; r < 4; ++r) dst[h * 4 + r] = oacc[t2][h][r];
#pragma unroll
            for (int r = 0; r < 4; ++r) dst[8 + r] = rsac[t2][r];
        }
    }
    __syncthreads();
    // reduce + write own q-tile (compile-time t2, wave-uniform guard)
#pragma unroll
    for (int t2 = 0; t2 < 4; ++t2) {
        if (t2 != w) continue;                         // wave-uniform branch
        float o0[4], o1[4], rsum[4];
#pragma unroll
        for (int r = 0; r < 4; ++r) {
            o0[r] = oacc[t2][0][r]; o1[r] = oacc[t2][1][r]; rsum[r] = rsac[t2][r];
        }
#pragma unroll
        for (int j = 0; j < 4; ++j) {
            if (j == t2) continue;
            const int slot = t2 - (t2 > j ? 1 : 0);    // runtime LDS offset: OK
            const float* srcp = &cmb[j][lane][slot * 12];
#pragma unroll
            for (int r = 0; r < 4; ++r) {
                o0[r]   += srcp[r];
                o1[r]   += srcp[4 + r];
                rsum[r] += srcp[8 + r];
            }
        }
        u16* Xb = X + (size_t)b * NSP * NCH + head * HD;
#pragma unroll
        for (int r = 0; r < 4; ++r) {
            const float inv = 1.f / rsum[r];
            u16* row = Xb + (size_t)(qbase + t2 * 16 + quad * 4 + r) * NCH;
            row[l15]      = f2bf(o0[r] * inv);
            row[16 + l15] = f2bf(o1[r] * inv);
        }
    }
}

// ---------------- 1x1 conv: out[b,o,n] = sum_c W[o,c] X[b,n,c] + bias[o] ----------------
// grid (NSP/64, NCH/64, NB), block 256 (4 waves): wave w does 16 o x 64 n.
__global__ __launch_bounds__(256) void proj_kernel(
    const u16* __restrict__ Wb, const u16* __restrict__ X,
    const float* __restrict__ bias, float* __restrict__ out)
{
    const int b = blockIdx.z;
    const int w = threadIdx.x >> 6, lane = threadIdx.x & 63;
    const int l15 = lane & 15, quad = lane >> 4;
    const int obase = blockIdx.y * 64 + w * 16;
    const int nbase = blockIdx.x * 64;

    const u16* wrow = Wb + (size_t)(obase + l15) * NCH + quad * 8;
    const u16* xrow = X + ((size_t)b * NSP + nbase + l15) * NCH + quad * 8;

    f32x4 acc[4] = {{0,0,0,0},{0,0,0,0},{0,0,0,0},{0,0,0,0}};
#pragma unroll
    for (int ks = 0; ks < 8; ++ks) {
        const short8 af = *(const short8*)(wrow + ks * 32);
#pragma unroll
        for (int jn = 0; jn < 4; ++jn) {
            const short8 bf = *(const short8*)(xrow + (size_t)jn * 16 * NCH + ks * 32);
            acc[jn] = __builtin_amdgcn_mfma_f32_16x16x32_bf16(af, bf, acc[jn], 0, 0, 0);
        }
    }
#pragma unroll
    for (int r = 0; r < 4; ++r) {
        const int o = obase + quad * 4 + r;
        const float bo = bias[o];
        float* orow = out + ((size_t)b * NCH + o) * NSP + nbase;
#pragma unroll
        for (int jn = 0; jn < 4; ++jn)
            orow[jn * 16 + l15] = acc[jn][r] + bo;
    }
}

extern "C" void kernel_launch(void* const* d_in, const int* in_sizes, int n_in,
                              void* d_out, int out_size, void* d_ws, size_t ws_size,
                              hipStream_t stream) {
    const float* qkv   = (const float*)d_in[0];
    const float* temp  = (const float*)d_in[1];
    const float* projw = (const float*)d_in[2];
    const float* projb = (const float*)d_in[3];
    float* out = (float*)d_out;

    // workspace: Qn | Kn | Vp | X (each 2,359,296 bf16) | Wb (65,536 bf16)  ~19 MB
    u16* Qn = (u16*)d_ws;
    u16* Kn = Qn + (size_t)NBH * NSP * HD;
    u16* Vp = Kn + (size_t)NBH * NSP * HD;
    u16* X  = Vp + (size_t)NBH * NSP * HD;
    u16* Wb = X + (size_t)NB * NSP * NCH;

    prep_kernel<<<dim3(NSP / 256, 4, NBH), dim3(256), 0, stream>>>(qkv, temp, projw, Qn, Kn, Vp, Wb);
    attn_kernel<<<dim3(NBH, NSP / 64), dim3(256), 0, stream>>>(Qn, Kn, Vp, X);
    proj_kernel<<<dim3(NSP / 64, NCH / 64, NB), dim3(256), 0, stream>>>(Wb, X, projb, out);
}